// Round 1
// baseline (215.236 us; speedup 1.0000x reference)
//
#include <hip/hip_runtime.h>
#include <hip/hip_bf16.h>

#define NROWS 100000
#define LDP   264   // LDS tile pitch in shorts: 256 + 8 pad (conflict-free b128 reads)

typedef short bf16x8 __attribute__((ext_vector_type(8)));
typedef float f32x4  __attribute__((ext_vector_type(4)));

__device__ __forceinline__ short f2bf(float f) {
    return __builtin_bit_cast(short, __float2bfloat16(f));
}

// ---- K0: Wmean[64][256] = 0.25 * sum_h Wv[h*64+d][k]  (fp32 -> bf16), bmean ----
__global__ __launch_bounds__(256) void k_prep(
    const float* __restrict__ Wv, const float* __restrict__ bv,
    short* __restrict__ Wmb, float* __restrict__ bmb)
{
    const int i = blockIdx.x * 256 + threadIdx.x;   // 0..16383
    const int d = i >> 8, k = i & 255;
    float s = 0.f;
#pragma unroll
    for (int h = 0; h < 4; ++h) s += Wv[(size_t)(h * 64 + d) * 256 + k];
    Wmb[i] = f2bf(0.25f * s);
    if (i < 64) {
        float b = 0.f;
#pragma unroll
        for (int h = 0; h < 4; ++h) b += bv[h * 64 + i];
        bmb[i] = 0.25f * b;
    }
}

// ---- K1: out[n][d] = xs[n] . Wmean[d] + bmean[d]  (MFMA 16x16x32 bf16) ----
// v2: x-tile staged through LDS with COALESCED global loads (the v1 direct
// fragment loads had consecutive lanes 1KB apart -> TA-pipe serialization).
// Fragment/MFMA/epilogue mapping identical to the verified v1 kernel.
__global__ __launch_bounds__(256, 2) void k_gemm(
    const float* __restrict__ xs, const short* __restrict__ Wmb,
    const float* __restrict__ bmb, float* __restrict__ out)
{
    __shared__ short lw[64][LDP];   // W tile, bf16
    __shared__ short lx[64][LDP];   // x tile, bf16
    __shared__ float lb[64];
    const int t = threadIdx.x;
    const int row0blk = blockIdx.x * 64;

    // stage W: 2048 16-B chunks, 8 per thread (L2-resident after block 0)
#pragma unroll
    for (int j = 0; j < 8; ++j) {
        const int c = t + j * 256;
        const int row = c >> 5, pos = (c & 31) << 3;   // pos in shorts
        *(bf16x8*)&lw[row][pos] = *(const bf16x8*)(Wmb + row * 256 + pos);
    }
    if (t < 64) lb[t] = bmb[t];

    // stage x tile: 64 rows x 256 f32, dense thread-consecutive f32x4 pairs,
    // convert to bf16 in regs, ds_write_b128. chunk c = 8 floats.
#pragma unroll
    for (int j = 0; j < 8; ++j) {
        const int c = t + j * 256;
        const int row = c >> 5, pos = (c & 31) << 3;
        const int grow = min(row0blk + row, NROWS - 1);   // tail clamp (stores guarded)
        const float* gp = xs + (size_t)grow * 256 + pos;
        const f32x4 xa = *(const f32x4*)gp;
        const f32x4 xb = *(const f32x4*)(gp + 4);
        bf16x8 v;
        v[0] = f2bf(xa[0]); v[1] = f2bf(xa[1]); v[2] = f2bf(xa[2]); v[3] = f2bf(xa[3]);
        v[4] = f2bf(xb[0]); v[5] = f2bf(xb[1]); v[6] = f2bf(xb[2]); v[7] = f2bf(xb[3]);
        *(bf16x8*)&lx[row][pos] = v;
    }
    __syncthreads();

    const int wave = t >> 6, lane = t & 63;
    const int lrow = lane & 15, quad = lane >> 4;

    f32x4 acc[4] = {};
#pragma unroll
    for (int k0 = 0; k0 < 256; k0 += 32) {
        const bf16x8 a = *(const bf16x8*)&lx[wave * 16 + lrow][k0 + quad * 8];
#pragma unroll
        for (int c = 0; c < 4; ++c) {
            const bf16x8 b = *(const bf16x8*)&lw[c * 16 + lrow][k0 + quad * 8];
            acc[c] = __builtin_amdgcn_mfma_f32_16x16x32_bf16(a, b, acc[c], 0, 0, 0);
        }
    }

    // epilogue: bias + fp32 store. For fixed (c,r): 16 lanes write 64 B
    // contiguous per quad-row -> full 64-B segments.
    const int row0 = row0blk + wave * 16;
#pragma unroll
    for (int c = 0; c < 4; ++c) {
        const float bias = lb[c * 16 + lrow];
#pragma unroll
        for (int r = 0; r < 4; ++r) {
            const int row = row0 + quad * 4 + r;
            if (row < NROWS)
                out[(size_t)row * 64 + c * 16 + lrow] = acc[c][r] + bias;
        }
    }
}

extern "C" void kernel_launch(void* const* d_in, const int* in_sizes, int n_in,
                              void* d_out, int out_size, void* d_ws, size_t ws_size,
                              hipStream_t stream)
{
    const float* xs = (const float*)d_in[1];   // source_input
    const float* Wv = (const float*)d_in[6];   // Wv_w [256][256]
    const float* bv = (const float*)d_in[7];   // Wv_b [256]

    char* ws = (char*)d_ws;
    short* Wmb = (short*)(ws + 0);       // 32 KB bf16 Wmean
    float* bmb = (float*)(ws + 32768);   // 256 B bmean

    k_prep<<<dim3(64),   256, 0, stream>>>(Wv, bv, Wmb, bmb);
    k_gemm<<<dim3(1563), 256, 0, stream>>>(xs, Wmb, bmb, (float*)d_out);
}

// Round 3
// 212.280 us; speedup vs baseline: 1.0139x; 1.0139x over previous
//
#include <hip/hip_runtime.h>
#include <hip/hip_bf16.h>

#define NROWS 100000
#define LDP   264   // LDS tile pitch in shorts: 256 + 8 pad (conflict-free b128 reads)

typedef short bf16x8 __attribute__((ext_vector_type(8)));
typedef float f32x4  __attribute__((ext_vector_type(4)));

__device__ __forceinline__ short f2bf(float f) {
    return __builtin_bit_cast(short, __float2bfloat16(f));
}

// ---- K0: Wmean[64][256] = 0.25 * sum_h Wv[h*64+d][k]  (fp32 -> bf16), bmean ----
__global__ __launch_bounds__(256) void k_prep(
    const float* __restrict__ Wv, const float* __restrict__ bv,
    short* __restrict__ Wmb, float* __restrict__ bmb)
{
    const int i = blockIdx.x * 256 + threadIdx.x;   // 0..16383
    const int d = i >> 8, k = i & 255;
    float s = 0.f;
#pragma unroll
    for (int h = 0; h < 4; ++h) s += Wv[(size_t)(h * 64 + d) * 256 + k];
    Wmb[i] = f2bf(0.25f * s);
    if (i < 64) {
        float b = 0.f;
#pragma unroll
        for (int h = 0; h < 4; ++h) b += bv[h * 64 + i];
        bmb[i] = 0.25f * b;
    }
}

// ---- K1: out[n][d] = xs[n] . Wmean[d] + bmean[d]  (MFMA 16x16x32 bf16) ----
// v3: issue-all-loads-first staging (wider MLP window), bias in registers
// (lb LDS removed), nontemporal xs loads / out stores (zero-reuse streams).
// Fragment/MFMA/epilogue mapping identical to the verified v2 kernel.
__global__ __launch_bounds__(256, 2) void k_gemm(
    const float* __restrict__ xs, const short* __restrict__ Wmb,
    const float* __restrict__ bmb, float* __restrict__ out)
{
    __shared__ short lw[64][LDP];   // W tile, bf16
    __shared__ short lx[64][LDP];   // x tile, bf16
    const int t = threadIdx.x;
    const int row0blk = blockIdx.x * 64;

    const int rbase = t >> 5;          // 0..7   (row within 8-row group)
    const int pos   = (t & 31) << 3;   // float/short offset 0..248, 8-elem chunk

    // ---- phase 1: issue ALL global loads into registers (max loads in flight) ----
    // x tile: 16x dwordx4 per thread (HBM, nontemporal - no reuse)
    f32x4 xv[16];
#pragma unroll
    for (int j = 0; j < 8; ++j) {
        const int grow = min(row0blk + rbase + j * 8, NROWS - 1);  // tail clamp
        const float* gp = xs + (size_t)grow * 256 + pos;
        xv[2 * j]     = __builtin_nontemporal_load((const f32x4*)gp);
        xv[2 * j + 1] = __builtin_nontemporal_load((const f32x4*)gp + 1);
    }
    // W tile: 8x dwordx4 per thread (L2-resident after first blocks)
    bf16x8 wv[8];
#pragma unroll
    for (int j = 0; j < 8; ++j) {
        const int c = t + j * 256;
        wv[j] = *(const bf16x8*)(Wmb + ((c >> 5) << 8) + ((c & 31) << 3));
    }
    // bias: 4 scalar loads (L2), kept in registers — no LDS round-trip
    const int lane = t & 63, lrow = lane & 15, quad = lane >> 4;
    float bias[4];
#pragma unroll
    for (int c = 0; c < 4; ++c) bias[c] = bmb[c * 16 + lrow];

    // ---- phase 2: convert + LDS writes ----
#pragma unroll
    for (int j = 0; j < 8; ++j) {
        const f32x4 a = xv[2 * j], b = xv[2 * j + 1];
        bf16x8 v;
        v[0] = f2bf(a[0]); v[1] = f2bf(a[1]); v[2] = f2bf(a[2]); v[3] = f2bf(a[3]);
        v[4] = f2bf(b[0]); v[5] = f2bf(b[1]); v[6] = f2bf(b[2]); v[7] = f2bf(b[3]);
        *(bf16x8*)&lx[rbase + j * 8][pos] = v;
    }
#pragma unroll
    for (int j = 0; j < 8; ++j) {
        const int c = t + j * 256;
        *(bf16x8*)&lw[c >> 5][(c & 31) << 3] = wv[j];
    }
    __syncthreads();

    // ---- phase 3: MFMA (verified m89 fragment pattern) ----
    f32x4 acc[4] = {};
#pragma unroll
    for (int k0 = 0; k0 < 256; k0 += 32) {
        const bf16x8 a = *(const bf16x8*)&lx[(t >> 6) * 16 + lrow][k0 + quad * 8];
#pragma unroll
        for (int c = 0; c < 4; ++c) {
            const bf16x8 b = *(const bf16x8*)&lw[c * 16 + lrow][k0 + quad * 8];
            acc[c] = __builtin_amdgcn_mfma_f32_16x16x32_bf16(a, b, acc[c], 0, 0, 0);
        }
    }

    // ---- epilogue: bias + fp32 nontemporal store. For fixed (c,r): 16 lanes
    // write 64 B contiguous per quad-row -> full 64-B segments.
    const int row0 = row0blk + (t >> 6) * 16;
#pragma unroll
    for (int c = 0; c < 4; ++c) {
#pragma unroll
        for (int r = 0; r < 4; ++r) {
            const int row = row0 + quad * 4 + r;
            if (row < NROWS)
                __builtin_nontemporal_store(acc[c][r] + bias[c],
                                            &out[(size_t)row * 64 + c * 16 + lrow]);
        }
    }
}

extern "C" void kernel_launch(void* const* d_in, const int* in_sizes, int n_in,
                              void* d_out, int out_size, void* d_ws, size_t ws_size,
                              hipStream_t stream)
{
    const float* xs = (const float*)d_in[1];   // source_input
    const float* Wv = (const float*)d_in[6];   // Wv_w [256][256]
    const float* bv = (const float*)d_in[7];   // Wv_b [256]

    char* ws = (char*)d_ws;
    short* Wmb = (short*)(ws + 0);       // 32 KB bf16 Wmean
    float* bmb = (float*)(ws + 32768);   // 256 B bmean

    k_prep<<<dim3(64),   256, 0, stream>>>(Wv, bv, Wmb, bmb);
    k_gemm<<<dim3(1563), 256, 0, stream>>>(xs, Wmb, bmb, (float*)d_out);
}

// Round 4
// 211.085 us; speedup vs baseline: 1.0197x; 1.0057x over previous
//
#include <hip/hip_runtime.h>
#include <hip/hip_bf16.h>

#define NROWS 100000
#define NTILES 1563            // ceil(100000/64)
#define GRID   512             // 2 blocks/CU x 256 CU = exact resident capacity
#define LDP    264             // LDS tile pitch in shorts: 256 + 8 pad (2-way max on b128 reads)

typedef short bf16x8 __attribute__((ext_vector_type(8)));
typedef float f32x4  __attribute__((ext_vector_type(4)));

__device__ __forceinline__ short f2bf(float f) {
    return __builtin_bit_cast(short, __float2bfloat16(f));
}

// ---- K0: Wmean[64][256] = 0.25 * sum_h Wv[h*64+d][k]  (fp32 -> bf16), bmean ----
__global__ __launch_bounds__(256) void k_prep(
    const float* __restrict__ Wv, const float* __restrict__ bv,
    short* __restrict__ Wmb, float* __restrict__ bmb)
{
    const int i = blockIdx.x * 256 + threadIdx.x;   // 0..16383
    const int d = i >> 8, k = i & 255;
    float s = 0.f;
#pragma unroll
    for (int h = 0; h < 4; ++h) s += Wv[(size_t)(h * 64 + d) * 256 + k];
    Wmb[i] = f2bf(0.25f * s);
    if (i < 64) {
        float b = 0.f;
#pragma unroll
        for (int h = 0; h < 4; ++h) b += bv[h * 64 + i];
        bmb[i] = 0.25f * b;
    }
}

// ---- K1: out[n][d] = xs[n] . Wmean[d] + bmean[d]  (MFMA 16x16x32 bf16) ----
// v4: persistent blocks (512 = resident capacity), grid-stride over 1563
// 64-row tiles. W staged into LDS ONCE per block (not per tile); next tile's
// 16 global loads issued right after the barrier so they fly under the
// current tile's MFMA + epilogue (T14 async-STAGE split, depth 1).
// Fragment/MFMA/epilogue mapping identical to the verified v3 kernel.
__global__ __launch_bounds__(256, 2) void k_gemm(
    const float* __restrict__ xs, const short* __restrict__ Wmb,
    const float* __restrict__ bmb, float* __restrict__ out)
{
    __shared__ short lw[64][LDP];   // W tile, bf16 (staged once)
    __shared__ short lx[64][LDP];   // x tile, bf16 (recycled per tile)
    const int t = threadIdx.x;

    const int rbase = t >> 5;          // 0..7   (row within 8-row group)
    const int pos   = (t & 31) << 3;   // float/short offset 0..248, 8-elem chunk
    const int lane = t & 63, lrow = lane & 15, quad = lane >> 4;

    // ---- prologue: issue first x tile + W + bias loads (max loads in flight) ----
    int tile = blockIdx.x;
    f32x4 xv[16];
#pragma unroll
    for (int j = 0; j < 8; ++j) {
        const int grow = min(tile * 64 + rbase + j * 8, NROWS - 1);  // tail clamp
        const float* gp = xs + (size_t)grow * 256 + pos;
        xv[2 * j]     = __builtin_nontemporal_load((const f32x4*)gp);
        xv[2 * j + 1] = __builtin_nontemporal_load((const f32x4*)gp + 1);
    }
    bf16x8 wv[8];
#pragma unroll
    for (int j = 0; j < 8; ++j) {
        const int c = t + j * 256;
        wv[j] = *(const bf16x8*)(Wmb + ((c >> 5) << 8) + ((c & 31) << 3));
    }
    float bias[4];
#pragma unroll
    for (int c = 0; c < 4; ++c) bias[c] = bmb[c * 16 + lrow];

    // stage W once
#pragma unroll
    for (int j = 0; j < 8; ++j) {
        const int c = t + j * 256;
        *(bf16x8*)&lw[c >> 5][(c & 31) << 3] = wv[j];
    }

    // ---- persistent tile loop ----
    while (true) {
        // convert current x tile + LDS write (vmcnt wait on xv lands here)
#pragma unroll
        for (int j = 0; j < 8; ++j) {
            const f32x4 a = xv[2 * j], b = xv[2 * j + 1];
            bf16x8 v;
            v[0] = f2bf(a[0]); v[1] = f2bf(a[1]); v[2] = f2bf(a[2]); v[3] = f2bf(a[3]);
            v[4] = f2bf(b[0]); v[5] = f2bf(b[1]); v[6] = f2bf(b[2]); v[7] = f2bf(b[3]);
            *(bf16x8*)&lx[rbase + j * 8][pos] = v;
        }
        __syncthreads();   // lx (and, first iter, lw) visible to all waves

        // prefetch next tile's x into registers — flies under MFMA + stores
        const int next = tile + GRID;
        if (next < NTILES) {
#pragma unroll
            for (int j = 0; j < 8; ++j) {
                const int grow = min(next * 64 + rbase + j * 8, NROWS - 1);
                const float* gp = xs + (size_t)grow * 256 + pos;
                xv[2 * j]     = __builtin_nontemporal_load((const f32x4*)gp);
                xv[2 * j + 1] = __builtin_nontemporal_load((const f32x4*)gp + 1);
            }
        }

        // MFMA (verified m89 fragment pattern)
        f32x4 acc[4] = {};
#pragma unroll
        for (int k0 = 0; k0 < 256; k0 += 32) {
            const bf16x8 a = *(const bf16x8*)&lx[(t >> 6) * 16 + lrow][k0 + quad * 8];
#pragma unroll
            for (int c = 0; c < 4; ++c) {
                const bf16x8 b = *(const bf16x8*)&lw[c * 16 + lrow][k0 + quad * 8];
                acc[c] = __builtin_amdgcn_mfma_f32_16x16x32_bf16(a, b, acc[c], 0, 0, 0);
            }
        }

        // epilogue: bias + fp32 nontemporal store. For fixed (c,r): 16 lanes
        // write 64 B contiguous per quad-row -> full 64-B segments.
        const int row0 = tile * 64 + (t >> 6) * 16;
#pragma unroll
        for (int c = 0; c < 4; ++c) {
#pragma unroll
            for (int r = 0; r < 4; ++r) {
                const int row = row0 + quad * 4 + r;
                if (row < NROWS)
                    __builtin_nontemporal_store(acc[c][r] + bias[c],
                                                &out[(size_t)row * 64 + c * 16 + lrow]);
            }
        }

        if (next >= NTILES) break;
        tile = next;
        __syncthreads();   // all waves done reading lx before overwrite
    }
}

extern "C" void kernel_launch(void* const* d_in, const int* in_sizes, int n_in,
                              void* d_out, int out_size, void* d_ws, size_t ws_size,
                              hipStream_t stream)
{
    const float* xs = (const float*)d_in[1];   // source_input
    const float* Wv = (const float*)d_in[6];   // Wv_w [256][256]
    const float* bv = (const float*)d_in[7];   // Wv_b [256]

    char* ws = (char*)d_ws;
    short* Wmb = (short*)(ws + 0);       // 32 KB bf16 Wmean
    float* bmb = (float*)(ws + 32768);   // 256 B bmean

    k_prep<<<dim3(64),   256, 0, stream>>>(Wv, bv, Wmb, bmb);
    k_gemm<<<dim3(GRID), 256, 0, stream>>>(xs, Wmb, bmb, (float*)d_out);
}